// Round 1
// baseline (222.393 us; speedup 1.0000x reference)
//
#include <hip/hip_runtime.h>

#define BLOCK 256
#define MAX_M 2048

__global__ __launch_bounds__(BLOCK) void gauss_map_kernel(
    const int* __restrict__ li_coors, int n_li,
    const int* __restrict__ ra_coors, int n_ra,
    const float* __restrict__ ra_pts,
    const int* __restrict__ ra_vox,
    int m,
    float* __restrict__ out)
{
    __shared__ float sx[MAX_M];
    __shared__ float sy[MAX_M];
    __shared__ int s_count;

    if (threadIdx.x == 0) s_count = 0;
    __syncthreads();

    // Stage candidates into LDS; invalid -> far sentinel (3e4; any valid
    // distance^2 <= 2*513^2 ~ 5.3e5 << 9e8 so sentinel never wins the min).
    int local = 0;
    for (int i = threadIdx.x; i < m; i += BLOCK) {
        float v = ra_pts[i * 5 + 4];
        bool valid = fabsf(v) > 0.1f;
        local += valid ? 1 : 0;
        sx[i] = valid ? (float)ra_vox[i * 3 + 1] : 3.0e4f;
        sy[i] = valid ? (float)ra_vox[i * 3 + 2] : 3.0e4f;
    }
    if (local) atomicAdd(&s_count, local);   // compiler coalesces per-wave
    __syncthreads();
    const int count = s_count;

    const int li_total = n_li * 9;
    const int total = (n_li + n_ra) * 9;
    int q = blockIdx.x * BLOCK + threadIdx.x;
    if (q >= total) return;

    // Decode (point, shift)
    const int shift_x[9] = {0,-1,1,0,-1,1,0,-1,1};
    const int shift_y[9] = {0, 0,0,1, 1,1,-1,-1,-1};
    int n, s;
    const int* __restrict__ src;
    if (q < li_total) { n = q / 9; s = q - n * 9; src = li_coors; }
    else { int r = q - li_total; n = r / 9; s = r - n * 9; src = ra_coors; }

    int cx = src[n * 2 + 0] + shift_x[s];
    int cy = src[n * 2 + 1] + shift_y[s];
    // coords in [0,511], shifts in {-1,0,1} -> range [-1,512]; mod 513:
    if (cx < 0) cx += 513;
    if (cy < 0) cy += 513;
    const float qx = (float)cx;
    const float qy = (float)cy;

    float best = 3.4e38f;
#pragma unroll 8
    for (int i = 0; i < MAX_M; ++i) {
        if (i >= m) break;
        float dx = qx - sx[i];
        float dy = qy - sy[i];
        float d2 = fmaf(dx, dx, dy * dy);
        best = fminf(best, d2);
    }

    float dis = (count > 1) ? sqrtf(best) * 0.01f : 0.0f;
    out[q] = dis;
}

extern "C" void kernel_launch(void* const* d_in, const int* in_sizes, int n_in,
                              void* d_out, int out_size, void* d_ws, size_t ws_size,
                              hipStream_t stream) {
    const int*   li  = (const int*)d_in[0];
    const int*   ra  = (const int*)d_in[1];
    const float* pts = (const float*)d_in[2];
    const int*   vox = (const int*)d_in[3];
    float* out = (float*)d_out;

    const int n_li = in_sizes[0] / 2;
    const int n_ra = in_sizes[1] / 2;
    const int m    = in_sizes[2] / 5;

    const int total = (n_li + n_ra) * 9;
    const int blocks = (total + BLOCK - 1) / BLOCK;

    gauss_map_kernel<<<blocks, BLOCK, 0, stream>>>(li, n_li, ra, n_ra, pts, vox, m, out);
}

// Round 2
// 80.254 us; speedup vs baseline: 2.7711x; 2.7711x over previous
//
#include <hip/hip_runtime.h>

#define BLOCK 256
#define SPLITS 8
#define MAXC 264   // max padded candidate chunk (m<=2048 -> chunk 256)

__device__ __forceinline__ float d2f(float qx, float qy, float cx, float cy) {
    float dx = qx - cx;
    float dy = qy - cy;
    return fmaf(dx, dx, dy * dy);
}

__global__ __launch_bounds__(BLOCK) void partial_kernel(
    const int* __restrict__ li_coors, int n_li,
    const int* __restrict__ ra_coors, int n_ra,
    const float* __restrict__ pts,
    const int* __restrict__ vox,
    int m, int cs, int csPad,
    int* __restrict__ out_bits,   // d_out viewed as int bits; pre-init 0x7F7F7F7F
    int* __restrict__ counter)    // zero-initialized
{
    __shared__ float2 sc[MAXC];

    // Stage this split's candidate chunk into LDS as packed (x,y).
    // Invalid/pad -> sentinel 3e4 (d2 ~ 1.8e9, always loses to any valid
    // candidate: valid d2 <= 2*513^2 ~ 5.3e5; gate count>1 covers all-invalid).
    const int base = blockIdx.y * cs;
    int nvalid = 0;
    for (int i = threadIdx.x; i < csPad; i += BLOCK) {
        int gi = base + i;
        float x = 3.0e4f, y = 3.0e4f;
        bool valid = false;
        if (i < cs && gi < m) {
            valid = fabsf(pts[gi * 5 + 4]) > 0.1f;
            if (valid) { x = (float)vox[gi * 3 + 1]; y = (float)vox[gi * 3 + 2]; }
        }
        sc[i] = make_float2(x, y);
        nvalid += valid ? 1 : 0;
    }
    // Count each candidate exactly once (only the blockIdx.x==0 row counts).
    if (blockIdx.x == 0 && nvalid) atomicAdd(counter, nvalid);
    __syncthreads();

    const int li_total = n_li * 9;
    const int total = (n_li + n_ra) * 9;
    const int q = blockIdx.x * BLOCK + threadIdx.x;
    if (q >= total) return;

    // Decode (point, shift)
    const int shift_x[9] = {0,-1,1,0,-1,1,0,-1,1};
    const int shift_y[9] = {0, 0,0,1, 1,1,-1,-1,-1};
    int n, s;
    const int* __restrict__ src;
    if (q < li_total) { n = q / 9; s = q - n * 9; src = li_coors; }
    else { int r = q - li_total; n = r / 9; s = r - n * 9; src = ra_coors; }

    int cx = src[n * 2 + 0] + shift_x[s];
    int cy = src[n * 2 + 1] + shift_y[s];
    if (cx < 0) cx += 513;   // coords in [0,511], shift in {-1,0,1}
    if (cy < 0) cy += 513;
    const float qx = (float)cx;
    const float qy = (float)cy;

    // 8 candidates per iteration via 4x ds_read_b128, 4 independent min chains.
    const float4* __restrict__ s4 = (const float4*)sc;
    float m0 = 3.4e38f, m1 = 3.4e38f, m2 = 3.4e38f, m3 = 3.4e38f;
    const int iters = csPad >> 3;
    for (int i = 0; i < iters; ++i) {
        float4 a = s4[4 * i + 0];
        float4 b = s4[4 * i + 1];
        float4 c = s4[4 * i + 2];
        float4 d = s4[4 * i + 3];
        m0 = fminf(m0, d2f(qx, qy, a.x, a.y));
        m1 = fminf(m1, d2f(qx, qy, b.x, b.y));
        m2 = fminf(m2, d2f(qx, qy, c.x, c.y));
        m3 = fminf(m3, d2f(qx, qy, d.x, d.y));
        m0 = fminf(m0, d2f(qx, qy, a.z, a.w));
        m1 = fminf(m1, d2f(qx, qy, b.z, b.w));
        m2 = fminf(m2, d2f(qx, qy, c.z, c.w));
        m3 = fminf(m3, d2f(qx, qy, d.z, d.w));
    }
    float best = fminf(fminf(m0, m1), fminf(m2, m3));

    // d2 >= 0 so fp32 bit pattern compares correctly as signed int.
    atomicMin(out_bits + q, __float_as_int(best));
}

__global__ __launch_bounds__(BLOCK) void finalize_kernel(
    float* __restrict__ out, int total, const int* __restrict__ counter)
{
    int q = blockIdx.x * BLOCK + threadIdx.x;
    if (q >= total) return;
    float d2 = out[q];          // still holds min d2 (bits written by atomicMin)
    int cnt = *counter;
    out[q] = (cnt > 1) ? sqrtf(d2) * 0.01f : 0.0f;
}

extern "C" void kernel_launch(void* const* d_in, const int* in_sizes, int n_in,
                              void* d_out, int out_size, void* d_ws, size_t ws_size,
                              hipStream_t stream) {
    const int*   li  = (const int*)d_in[0];
    const int*   ra  = (const int*)d_in[1];
    const float* pts = (const float*)d_in[2];
    const int*   vox = (const int*)d_in[3];
    float* out = (float*)d_out;
    int*   counter = (int*)d_ws;

    const int n_li = in_sizes[0] / 2;
    const int n_ra = in_sizes[1] / 2;
    const int m    = in_sizes[2] / 5;

    const int total = (n_li + n_ra) * 9;
    const int qblocks = (total + BLOCK - 1) / BLOCK;

    const int cs    = (m + SPLITS - 1) / SPLITS;
    const int csPad = (cs + 7) & ~7;   // multiple of 8; <= MAXC for m<=2048

    // out <- 0x7F7F7F7F bytes = 3.39e38f (bigger than any d2 incl. sentinel)
    hipMemsetAsync(d_out, 0x7F, (size_t)total * sizeof(float), stream);
    hipMemsetAsync(d_ws, 0, sizeof(int), stream);

    dim3 grid(qblocks, SPLITS);
    partial_kernel<<<grid, BLOCK, 0, stream>>>(li, n_li, ra, n_ra, pts, vox,
                                               m, cs, csPad,
                                               (int*)d_out, counter);
    finalize_kernel<<<qblocks, BLOCK, 0, stream>>>(out, total, counter);
}